// Round 1
// baseline (285.414 us; speedup 1.0000x reference)
//
#include <hip/hip_runtime.h>
#include <hip/hip_bf16.h>
#include <cstddef>

#define Nn 12288
#define Cc 64

typedef __bf16 bf16x8 __attribute__((ext_vector_type(8)));
typedef float  f32x4  __attribute__((ext_vector_type(4)));
typedef int    i32x4  __attribute__((ext_vector_type(4)));

// Kernel 1: wh = x @ W (fp32 compute), store whT[c][j] in bf16 for MFMA B-operand,
// plus src[i] = wh[i]·a_src, dst[i] = wh[i]·a_dst.
__global__ __launch_bounds__(256) void prep_kernel(
    const float* __restrict__ x, const float* __restrict__ W,
    const float* __restrict__ wa, __bf16* __restrict__ whT,
    float* __restrict__ src, float* __restrict__ dst)
{
    __shared__ float Wl[64 * 64];
    __shared__ float Xl[4 * 64];
    int t = threadIdx.x;
    for (int k = t; k < 64 * 64; k += 256) Wl[k] = W[k];
    Xl[t] = x[(size_t)blockIdx.x * 256 + t];
    __syncthreads();
    int c   = t & 63;
    int row = blockIdx.x * 4 + (t >> 6);
    const float* xr = Xl + (t >> 6) * 64;
    float val = 0.f;
    #pragma unroll
    for (int k = 0; k < 64; ++k) val = fmaf(xr[k], Wl[k * 64 + c], val);
    float s = val * wa[c];
    float d = val * wa[64 + c];
    #pragma unroll
    for (int off = 32; off; off >>= 1) {
        s += __shfl_xor(s, off);
        d += __shfl_xor(d, off);
    }
    if (c == 0) { src[row] = s; dst[row] = d; }
    whT[c * Nn + row] = (__bf16)val;   // scatter; whT is tiny (1.5 MB), L2 absorbs
}

// Kernel 2: per wave: 16 rows x one j-segment. P computed straight into the
// mfma_f32_16x16x32_bf16 A-fragment layout; 4 MFMAs per 32-j chunk accumulate
// the unnormalized numerator; Z accumulated lane-locally (same values).
template <int NSEG>
__global__ __launch_bounds__(256) void attn_kernel(
    const int* __restrict__ mask, const __bf16* __restrict__ whT,
    const float* __restrict__ src, const float* __restrict__ dstv,
    float* __restrict__ pnum, float* __restrict__ pz)
{
    int lane = threadIdx.x & 63;
    int w    = blockIdx.x * 4 + (threadIdx.x >> 6);
    int g    = w / NSEG, seg = w % NSEG;
    int row  = lane & 15;          // A-fragment row / B-fragment col
    int kg   = lane >> 4;          // k-group
    int grow = g * 16 + row;
    float srow = src[grow];
    const int* mrow = mask + (size_t)grow * Nn;
    constexpr int CHUNKS = (Nn / 32) / NSEG;
    int j0 = seg * (Nn / NSEG) + kg * 8;
    f32x4 acc0 = {0.f, 0.f, 0.f, 0.f}, acc1 = acc0, acc2 = acc0, acc3 = acc0;
    float zacc = 0.f;
    const __bf16* wcol0 = whT + (size_t)row * Nn;
    for (int it = 0; it < CHUNKS; ++it, j0 += 32) {
        i32x4 m0 = *(const i32x4*)(mrow + j0);
        i32x4 m1 = *(const i32x4*)(mrow + j0 + 4);
        f32x4 d0 = *(const f32x4*)(dstv + j0);
        f32x4 d1 = *(const f32x4*)(dstv + j0 + 4);
        bf16x8 pa;
        #pragma unroll
        for (int e = 0; e < 4; ++e) {
            float tt = srow + d0[e];
            float f  = fmaxf(tt, 0.01f * tt);   // leaky_relu, slope 0.01
            float wv = __expf(f);
            wv = (m0[e] > 0) ? wv : 0.f;
            zacc += wv;
            pa[e] = (__bf16)wv;
        }
        #pragma unroll
        for (int e = 0; e < 4; ++e) {
            float tt = srow + d1[e];
            float f  = fmaxf(tt, 0.01f * tt);
            float wv = __expf(f);
            wv = (m1[e] > 0) ? wv : 0.f;
            zacc += wv;
            pa[4 + e] = (__bf16)wv;
        }
        bf16x8 b0 = *(const bf16x8*)(wcol0 + j0);
        bf16x8 b1 = *(const bf16x8*)(wcol0 + 16 * Nn + j0);
        bf16x8 b2 = *(const bf16x8*)(wcol0 + 32 * Nn + j0);
        bf16x8 b3 = *(const bf16x8*)(wcol0 + 48 * Nn + j0);
        acc0 = __builtin_amdgcn_mfma_f32_16x16x32_bf16(pa, b0, acc0, 0, 0, 0);
        acc1 = __builtin_amdgcn_mfma_f32_16x16x32_bf16(pa, b1, acc1, 0, 0, 0);
        acc2 = __builtin_amdgcn_mfma_f32_16x16x32_bf16(pa, b2, acc2, 0, 0, 0);
        acc3 = __builtin_amdgcn_mfma_f32_16x16x32_bf16(pa, b3, acc3, 0, 0, 0);
    }
    // Z: lanes {l, l+16, l+32, l+48} share a row -> xor-16 + xor-32 reduce
    zacc += __shfl_xor(zacc, 16);
    zacc += __shfl_xor(zacc, 32);
    float* np = pnum + ((size_t)seg * Nn + g * 16) * 64;
    #pragma unroll
    for (int r = 0; r < 4; ++r) {
        int orow = kg * 4 + r;      // C/D: row = 4*(lane>>4)+reg, col = lane&15 (m89)
        np[orow * 64 + row     ] = acc0[r];
        np[orow * 64 + row + 16] = acc1[r];
        np[orow * 64 + row + 32] = acc2[r];
        np[orow * 64 + row + 48] = acc3[r];
    }
    if (lane < 16) pz[(size_t)seg * Nn + g * 16 + lane] = zacc;
}

// Kernel 3: combine segment partials, normalize, add bias.
__global__ __launch_bounds__(256) void finalize_kernel(
    const float* __restrict__ pnum, const float* __restrict__ pz,
    const float* __restrict__ bias, float* __restrict__ out, int nseg)
{
    int idx = blockIdx.x * 256 + threadIdx.x;
    int i = idx >> 6, c = idx & 63;
    float num = 0.f, z = 0.f;
    for (int s = 0; s < nseg; ++s) {
        num += pnum[(size_t)s * Nn * 64 + idx];
        z   += pz[(size_t)s * Nn + i];
    }
    z = (z != 0.f) ? z : 1.f;     // unreachable for this input distribution
    out[idx] = num / z + bias[c];
}

extern "C" void kernel_launch(void* const* d_in, const int* in_sizes, int n_in,
                              void* d_out, int out_size, void* d_ws, size_t ws_size,
                              hipStream_t stream) {
    const float* x    = (const float*)d_in[0];
    const int*   mask = (const int*)d_in[1];
    const float* W    = (const float*)d_in[2];
    const float* wa   = (const float*)d_in[3];
    const float* bias = (const float*)d_in[4];
    float* out = (float*)d_out;

    char* ws = (char*)d_ws;
    const size_t whT_bytes = (size_t)Nn * 64 * 2;   // 1.5 MB
    const size_t vec_bytes = (size_t)Nn * 4;        // 48 KB
    __bf16* whT = (__bf16*)ws;
    float*  src = (float*)(ws + whT_bytes);
    float*  dst = (float*)(ws + whT_bytes + vec_bytes);
    size_t fixed = whT_bytes + 2 * vec_bytes;
    size_t per_seg = (size_t)Nn * 64 * 4 + (size_t)Nn * 4;

    int nseg = 8;
    while (nseg > 1 && fixed + (size_t)nseg * per_seg > ws_size) nseg >>= 1;

    float* pnum = (float*)(ws + fixed);
    float* pz   = (float*)(ws + fixed + (size_t)nseg * Nn * 64 * 4);

    prep_kernel<<<Nn / 4, 256, 0, stream>>>(x, W, wa, whT, src, dst);

    int blocks = 192 * nseg;   // 768 row-groups * nseg waves, 4 waves/block
    switch (nseg) {
        case 8: attn_kernel<8><<<blocks, 256, 0, stream>>>(mask, whT, src, dst, pnum, pz); break;
        case 4: attn_kernel<4><<<blocks, 256, 0, stream>>>(mask, whT, src, dst, pnum, pz); break;
        case 2: attn_kernel<2><<<blocks, 256, 0, stream>>>(mask, whT, src, dst, pnum, pz); break;
        default: attn_kernel<1><<<blocks, 256, 0, stream>>>(mask, whT, src, dst, pnum, pz); break;
    }

    finalize_kernel<<<(Nn * 64) / 256, 256, 0, stream>>>(pnum, pz, bias, out, nseg);
}

// Round 2
// 166.865 us; speedup vs baseline: 1.7104x; 1.7104x over previous
//
#include <hip/hip_runtime.h>
#include <hip/hip_bf16.h>
#include <cstddef>
#include <cstdint>

#define Nn 12288

typedef __bf16 bf16x8 __attribute__((ext_vector_type(8)));
typedef float  f32x4  __attribute__((ext_vector_type(4)));
typedef int    i32x4  __attribute__((ext_vector_type(4)));

__device__ __forceinline__ void gload_lds16(const void* g, void* l) {
    __builtin_amdgcn_global_load_lds(
        (const __attribute__((address_space(1))) void*)g,
        (__attribute__((address_space(3))) void*)l, 16, 0, 0);
}

// ---------------------------------------------------------------------------
// Kernel 1: wh = x @ W; emit whB in MFMA-fragment order, plus src/dst vectors.
// whB[(jc*4+q)*512 + lane*8 + e] = wh[jc*32 + (lane>>4)*8 + e][(lane&15) + 16q]
// Block: 64 rows of x. 192 blocks.
// ---------------------------------------------------------------------------
__global__ __launch_bounds__(256) void prep_kernel(
    const float* __restrict__ x, const float* __restrict__ W,
    const float* __restrict__ wa, __bf16* __restrict__ whB,
    float* __restrict__ src, float* __restrict__ dst)
{
    __shared__ float  Wl[64 * 64];     // [k][c]
    __shared__ float  Xl[64 * 64];     // [row][k]
    __shared__ __bf16 whl[64 * 72];    // [c][row] padded
    int t = threadIdx.x;
    int R0 = blockIdx.x * 64;
    for (int i = t; i < 4096; i += 256) {
        Wl[i] = W[i];
        Xl[i] = x[(size_t)R0 * 64 + i];
    }
    __syncthreads();
    int c   = t & 63;
    int r16 = (t >> 6) * 16;
    float vals[16];
    #pragma unroll
    for (int k = 0; k < 16; ++k) vals[k] = 0.f;
    #pragma unroll 16
    for (int kk = 0; kk < 64; ++kk) {
        float wv = Wl[kk * 64 + c];
        #pragma unroll
        for (int k = 0; k < 16; ++k)
            vals[k] = fmaf(Xl[(r16 + k) * 64 + kk], wv, vals[k]);
    }
    #pragma unroll
    for (int k = 0; k < 16; ++k) whl[c * 72 + r16 + k] = (__bf16)vals[k];
    __syncthreads();
    if (t < 64) {   // src/dst for row t
        float s = 0.f, d = 0.f;
        #pragma unroll 16
        for (int cc = 0; cc < 64; ++cc) {
            float v = (float)whl[cc * 72 + t];
            s = fmaf(v, wa[cc], s);
            d = fmaf(v, wa[64 + cc], d);
        }
        src[R0 + t] = s;
        dst[R0 + t] = d;
    }
    // whB: 512 groups of 8 bf16 per block; thread handles groups 2t, 2t+1
    #pragma unroll
    for (int gg = 0; gg < 2; ++gg) {
        int gidx   = t * 2 + gg;
        int jc_loc = gidx >> 8;
        int q      = (gidx >> 6) & 3;
        int lane   = gidx & 63;
        int crow   = (lane & 15) + 16 * q;
        int jrow   = jc_loc * 32 + (lane >> 4) * 8;
        bf16x8 v = *(const bf16x8*)&whl[crow * 72 + jrow];
        int jc = blockIdx.x * 2 + jc_loc;
        *(bf16x8*)&whB[((size_t)(jc * 4 + q) * 64 + lane) * 8] = v;
    }
}

// ---------------------------------------------------------------------------
// Kernel 2: fused mask->P->PV. Block = 16 rows x 1 segment, 4 waves.
// Mask tiles [16][256] staged via global_load_lds (1 KB contiguous per row),
// double-buffered; counted vmcnt(4); waves split the j-window of each tile.
// ---------------------------------------------------------------------------
__device__ __forceinline__ void chunk_mfma(
    float srow, i32x4 m0, i32x4 m1, f32x4 d0, f32x4 d1,
    bf16x8 b0, bf16x8 b1, bf16x8 b2, bf16x8 b3,
    f32x4& a0, f32x4& a1, f32x4& a2, f32x4& a3, float& zacc)
{
    bf16x8 pa;
    #pragma unroll
    for (int e = 0; e < 4; ++e) {
        float t0 = srow + d0[e];
        float f0 = fmaxf(t0, 0.01f * t0);      // leaky_relu(0.01)
        float w0 = __expf(f0);
        w0 = (m0[e] > 0) ? w0 : 0.f;
        zacc += w0;
        pa[e] = (__bf16)w0;
        float t1 = srow + d1[e];
        float f1 = fmaxf(t1, 0.01f * t1);
        float w1 = __expf(f1);
        w1 = (m1[e] > 0) ? w1 : 0.f;
        zacc += w1;
        pa[4 + e] = (__bf16)w1;
    }
    a0 = __builtin_amdgcn_mfma_f32_16x16x32_bf16(pa, b0, a0, 0, 0, 0);
    a1 = __builtin_amdgcn_mfma_f32_16x16x32_bf16(pa, b1, a1, 0, 0, 0);
    a2 = __builtin_amdgcn_mfma_f32_16x16x32_bf16(pa, b2, a2, 0, 0, 0);
    a3 = __builtin_amdgcn_mfma_f32_16x16x32_bf16(pa, b3, a3, 0, 0, 0);
}

template <int NSEG>
__global__ __launch_bounds__(256, 4) void attn_kernel(
    const int* __restrict__ mask, const __bf16* __restrict__ whB,
    const float* __restrict__ src, const float* __restrict__ dstv,
    float* __restrict__ pnum, float* __restrict__ pz)
{
    constexpr int NT = (Nn / NSEG) / 256;       // tiles per segment
    __shared__ int lm[2 * 16 * 260];            // dbuf mask tiles, 260-int row stride

    int t    = threadIdx.x;
    int lane = t & 63;
    int wid  = t >> 6;
    int g    = blockIdx.x / NSEG;
    int seg  = blockIdx.x % NSEG;
    int row  = lane & 15;
    int kg   = lane >> 4;
    int segbase = seg * (Nn / NSEG);
    float srow = src[g * 16 + row];

#define STAGE(b, tt)                                                          \
    do {                                                                      \
        _Pragma("unroll")                                                     \
        for (int rr = 0; rr < 4; ++rr) {                                      \
            int rs = wid * 4 + rr;                                            \
            const int* gp = mask + (size_t)(g * 16 + rs) * Nn + segbase +     \
                            (tt) * 256 + lane * 4;                            \
            gload_lds16(gp, &lm[(b) * 4160 + rs * 260]);                      \
        }                                                                     \
    } while (0)

    int cur = 0;
    STAGE(0, 0);
    f32x4 acc0 = {0.f, 0.f, 0.f, 0.f}, acc1 = acc0, acc2 = acc0, acc3 = acc0;
    float zacc = 0.f;

    for (int tt = 0; tt < NT; ++tt) {
        // 1. issue this tile's register loads (dst + whB) FIRST
        int jt = segbase + tt * 256 + wid * 64;   // wave's window base
        int jl = kg * 8;
        f32x4 d00 = *(const f32x4*)(dstv + jt + jl);
        f32x4 d01 = *(const f32x4*)(dstv + jt + jl + 4);
        f32x4 d10 = *(const f32x4*)(dstv + jt + 32 + jl);
        f32x4 d11 = *(const f32x4*)(dstv + jt + 32 + jl + 4);
        size_t jc0 = (size_t)(jt >> 5);
        const __bf16* wb0 = whB + (jc0 * 4) * 512 + lane * 8;
        const __bf16* wb1 = whB + ((jc0 + 1) * 4) * 512 + lane * 8;
        bf16x8 b00 = *(const bf16x8*)(wb0);
        bf16x8 b01 = *(const bf16x8*)(wb0 + 512);
        bf16x8 b02 = *(const bf16x8*)(wb0 + 1024);
        bf16x8 b03 = *(const bf16x8*)(wb0 + 1536);
        bf16x8 b10 = *(const bf16x8*)(wb1);
        bf16x8 b11 = *(const bf16x8*)(wb1 + 512);
        bf16x8 b12 = *(const bf16x8*)(wb1 + 1024);
        bf16x8 b13 = *(const bf16x8*)(wb1 + 1536);
        __builtin_amdgcn_sched_barrier(0);
        // 2. stage next tile
        if (tt + 1 < NT) {
            STAGE(cur ^ 1, tt + 1);
            // 3. retire everything except the 4 new stage loads
            asm volatile("s_waitcnt vmcnt(4)" ::: "memory");
        } else {
            asm volatile("s_waitcnt vmcnt(0)" ::: "memory");
        }
        __builtin_amdgcn_sched_barrier(0);
        __builtin_amdgcn_s_barrier();
        // 4. compute the 2 chunks of this wave's 64-j window
        const int* mbase = &lm[cur * 4160];
        i32x4 m00 = *(const i32x4*)&mbase[row * 260 + wid * 64 + jl];
        i32x4 m01 = *(const i32x4*)&mbase[row * 260 + wid * 64 + jl + 4];
        i32x4 m10 = *(const i32x4*)&mbase[row * 260 + wid * 64 + 32 + jl];
        i32x4 m11 = *(const i32x4*)&mbase[row * 260 + wid * 64 + 32 + jl + 4];
        chunk_mfma(srow, m00, m01, d00, d01, b00, b01, b02, b03,
                   acc0, acc1, acc2, acc3, zacc);
        chunk_mfma(srow, m10, m11, d10, d11, b10, b11, b12, b13,
                   acc0, acc1, acc2, acc3, zacc);
        __builtin_amdgcn_s_barrier();
        cur ^= 1;
    }
#undef STAGE

    // block reduce: 4 wave-partials -> one (16x64) tile + 16 z values
    float* red  = (float*)lm;          // [4][1024]
    float* redz = red + 4096;          // [4][16]
    #pragma unroll
    for (int r = 0; r < 4; ++r) {
        int orow = kg * 4 + r;         // C/D: row = 4*(lane>>4)+reg, col = lane&15
        red[wid * 1024 + orow * 64 + row]      = acc0[r];
        red[wid * 1024 + orow * 64 + row + 16] = acc1[r];
        red[wid * 1024 + orow * 64 + row + 32] = acc2[r];
        red[wid * 1024 + orow * 64 + row + 48] = acc3[r];
    }
    zacc += __shfl_xor(zacc, 16);
    zacc += __shfl_xor(zacc, 32);
    if (lane < 16) redz[wid * 16 + lane] = zacc;
    __syncthreads();
    #pragma unroll
    for (int k = 0; k < 4; ++k) {
        int idx = k * 256 + t;
        float sv = red[idx] + red[1024 + idx] + red[2048 + idx] + red[3072 + idx];
        pnum[(size_t)seg * Nn * 64 + (size_t)g * 1024 + idx] = sv;
    }
    if (t < 16)
        pz[(size_t)seg * Nn + g * 16 + t] =
            redz[t] + redz[16 + t] + redz[32 + t] + redz[48 + t];
}

// ---------------------------------------------------------------------------
// Kernel 3: combine segment partials, normalize, add bias.
// ---------------------------------------------------------------------------
__global__ __launch_bounds__(256) void finalize_kernel(
    const float* __restrict__ pnum, const float* __restrict__ pz,
    const float* __restrict__ bias, float* __restrict__ out, int nseg)
{
    int idx = blockIdx.x * 256 + threadIdx.x;
    int i = idx >> 6, c = idx & 63;
    float num = 0.f, z = 0.f;
    for (int s = 0; s < nseg; ++s) {
        num += pnum[(size_t)s * Nn * 64 + idx];
        z   += pz[(size_t)s * Nn + i];
    }
    z = (z != 0.f) ? z : 1.f;
    out[idx] = num / z + bias[c];
}

extern "C" void kernel_launch(void* const* d_in, const int* in_sizes, int n_in,
                              void* d_out, int out_size, void* d_ws, size_t ws_size,
                              hipStream_t stream) {
    const float* x    = (const float*)d_in[0];
    const int*   mask = (const int*)d_in[1];
    const float* W    = (const float*)d_in[2];
    const float* wa   = (const float*)d_in[3];
    const float* bias = (const float*)d_in[4];
    float* out = (float*)d_out;

    char* ws = (char*)d_ws;
    const size_t whB_bytes = (size_t)Nn * 64 * 2;   // 1.5 MB
    const size_t vec_bytes = (size_t)Nn * 4;        // 48 KB
    __bf16* whB = (__bf16*)ws;
    float*  src = (float*)(ws + whB_bytes);
    float*  dst = (float*)(ws + whB_bytes + vec_bytes);
    size_t fixed = whB_bytes + 2 * vec_bytes;
    size_t per_seg = (size_t)Nn * 64 * 4 + (size_t)Nn * 4;

    int nseg = 4;
    while (nseg > 1 && fixed + (size_t)nseg * per_seg > ws_size) nseg >>= 1;

    float* pnum = (float*)(ws + fixed);
    float* pz   = (float*)(ws + fixed + (size_t)nseg * Nn * 64 * 4);

    prep_kernel<<<Nn / 64, 256, 0, stream>>>(x, W, wa, whB, src, dst);

    int blocks = 768 * nseg;
    switch (nseg) {
        case 4: attn_kernel<4><<<blocks, 256, 0, stream>>>(mask, whB, src, dst, pnum, pz); break;
        case 2: attn_kernel<2><<<blocks, 256, 0, stream>>>(mask, whB, src, dst, pnum, pz); break;
        default: attn_kernel<1><<<blocks, 256, 0, stream>>>(mask, whB, src, dst, pnum, pz); break;
    }

    finalize_kernel<<<(Nn * 64) / 256, 256, 0, stream>>>(pnum, pz, bias, out, nseg);
}

// Round 4
// 142.854 us; speedup vs baseline: 1.9979x; 1.1681x over previous
//
#include <hip/hip_runtime.h>
#include <hip/hip_bf16.h>
#include <cstddef>
#include <cstdint>

#define Nn 12288
#define NTIL 48            // 12288 / 256 j per tile
#define MSTRIDE 264        // ints per mask row in LDS (16B-aligned, 2-way banks)
#define DSTOFF (2 * 16 * MSTRIDE)   // int offset of dst slots in lm

typedef __bf16 bf16x8 __attribute__((ext_vector_type(8)));
typedef float  f32x4  __attribute__((ext_vector_type(4)));
typedef int    i32x4  __attribute__((ext_vector_type(4)));

__device__ __forceinline__ void gload_lds16_nt(const void* g, void* l) {
    __builtin_amdgcn_global_load_lds(
        (const __attribute__((address_space(1))) void*)g,
        (__attribute__((address_space(3))) void*)l, 16, 0, 2 /*nt: don't thrash L2*/);
}
__device__ __forceinline__ void gload_lds4(const void* g, void* l) {
    __builtin_amdgcn_global_load_lds(
        (const __attribute__((address_space(1))) void*)g,
        (__attribute__((address_space(3))) void*)l, 4, 0, 0);
}

// ---------------------------------------------------------------------------
// Kernel 1 (unchanged, verified): wh = x @ W; whB in MFMA-fragment order;
// src/dst projection vectors.
// ---------------------------------------------------------------------------
__global__ __launch_bounds__(256) void prep_kernel(
    const float* __restrict__ x, const float* __restrict__ W,
    const float* __restrict__ wa, __bf16* __restrict__ whB,
    float* __restrict__ src, float* __restrict__ dst)
{
    __shared__ float  Wl[64 * 64];
    __shared__ float  Xl[64 * 64];
    __shared__ __bf16 whl[64 * 72];
    int t = threadIdx.x;
    int R0 = blockIdx.x * 64;
    for (int i = t; i < 4096; i += 256) {
        Wl[i] = W[i];
        Xl[i] = x[(size_t)R0 * 64 + i];
    }
    __syncthreads();
    int c   = t & 63;
    int r16 = (t >> 6) * 16;
    float vals[16];
    #pragma unroll
    for (int k = 0; k < 16; ++k) vals[k] = 0.f;
    #pragma unroll 16
    for (int kk = 0; kk < 64; ++kk) {
        float wv = Wl[kk * 64 + c];
        #pragma unroll
        for (int k = 0; k < 16; ++k)
            vals[k] = fmaf(Xl[(r16 + k) * 64 + kk], wv, vals[k]);
    }
    #pragma unroll
    for (int k = 0; k < 16; ++k) whl[c * 72 + r16 + k] = (__bf16)vals[k];
    __syncthreads();
    if (t < 64) {
        float s = 0.f, d = 0.f;
        #pragma unroll 16
        for (int cc = 0; cc < 64; ++cc) {
            float v = (float)whl[cc * 72 + t];
            s = fmaf(v, wa[cc], s);
            d = fmaf(v, wa[64 + cc], d);
        }
        src[R0 + t] = s;
        dst[R0 + t] = d;
    }
    #pragma unroll
    for (int gg = 0; gg < 2; ++gg) {
        int gidx   = t * 2 + gg;
        int jc_loc = gidx >> 8;
        int q      = (gidx >> 6) & 3;
        int lane   = gidx & 63;
        int crow   = (lane & 15) + 16 * q;
        int jrow   = jc_loc * 32 + (lane >> 4) * 8;
        bf16x8 v = *(const bf16x8*)&whl[crow * 72 + jrow];
        int jc = blockIdx.x * 2 + jc_loc;
        *(bf16x8*)&whB[((size_t)(jc * 4 + q) * 64 + lane) * 8] = v;
    }
}

// ---------------------------------------------------------------------------
// Kernel 2: block = 16 rows x full j (NSEG=1). Per tile (256 j):
//   stage: 4x gload_lds16(nt) mask rows + 1x gload_lds4 dst window (per wave)
//   b-operands: 8x inline-asm global_load_dwordx4 (flat 64b vaddr form),
//   double-buffered reg sets; constant vmcnt(13): one tile ahead, never drain.
// ---------------------------------------------------------------------------
__global__ __launch_bounds__(256) void attn_kernel(
    const int* __restrict__ mask, const __bf16* __restrict__ whB,
    const float* __restrict__ src, const float* __restrict__ dstv,
    const float* __restrict__ bias, float* __restrict__ out)
{
    __shared__ int lm[DSTOFF + 2 * 256];   // mask dbuf [2][16][264] + dst dbuf [2][4][64]

    int t    = threadIdx.x;
    int lane = t & 63;
    int wid  = t >> 6;
    int g    = blockIdx.x;
    int row  = lane & 15;
    int kg   = lane >> 4;
    int jl   = kg * 8;

    float srow = src[g * 16 + row];
    asm volatile("" :: "v"(srow));   // resolve before pipeline starts

    i32x4 bset[2][8];
    f32x4 acc0 = {0.f, 0.f, 0.f, 0.f}, acc1 = acc0, acc2 = acc0, acc3 = acc0;
    float zacc = 0.f;

#define STAGE(B, TT)                                                          \
    do {                                                                      \
        _Pragma("unroll")                                                     \
        for (int rr = 0; rr < 4; ++rr) {                                      \
            int rs = wid * 4 + rr;                                            \
            gload_lds16_nt(mask + (size_t)(g * 16 + rs) * Nn + (TT) * 256 +   \
                               lane * 4,                                      \
                           &lm[(B) * 4224 + rs * MSTRIDE]);                   \
        }                                                                     \
        gload_lds4(dstv + (TT) * 256 + wid * 64 + lane,                       \
                   &lm[DSTOFF + (B) * 256 + wid * 64]);                       \
    } while (0)

#define BLOAD(P, TT)                                                          \
    do {                                                                      \
        const char* _b0 = (const char*)whB +                                  \
                          ((size_t)((TT) * 8 + wid * 2)) * 4096 +             \
                          (size_t)lane * 16;                                  \
        const char* _b1 = _b0 + 4096;                                         \
        asm volatile("global_load_dwordx4 %0, %1, off"                        \
                     : "=v"(bset[P][0]) : "v"(_b0));                          \
        asm volatile("global_load_dwordx4 %0, %1, off offset:1024"            \
                     : "=v"(bset[P][1]) : "v"(_b0));                          \
        asm volatile("global_load_dwordx4 %0, %1, off offset:2048"            \
                     : "=v"(bset[P][2]) : "v"(_b0));                          \
        asm volatile("global_load_dwordx4 %0, %1, off offset:3072"            \
                     : "=v"(bset[P][3]) : "v"(_b0));                          \
        asm volatile("global_load_dwordx4 %0, %1, off"                        \
                     : "=v"(bset[P][4]) : "v"(_b1));                          \
        asm volatile("global_load_dwordx4 %0, %1, off offset:1024"            \
                     : "=v"(bset[P][5]) : "v"(_b1));                          \
        asm volatile("global_load_dwordx4 %0, %1, off offset:2048"            \
                     : "=v"(bset[P][6]) : "v"(_b1));                          \
        asm volatile("global_load_dwordx4 %0, %1, off offset:3072"            \
                     : "=v"(bset[P][7]) : "v"(_b1));                          \
    } while (0)

#define COMPUTE(TT, B, P)                                                     \
    do {                                                                      \
        const int*   mb = &lm[(B) * 4224 + row * MSTRIDE + wid * 64];         \
        const float* db = (const float*)&lm[DSTOFF + (B) * 256 + wid * 64];   \
        _Pragma("unroll")                                                     \
        for (int cc = 0; cc < 2; ++cc) {                                      \
            i32x4 m0 = *(const i32x4*)(mb + cc * 32 + jl);                    \
            i32x4 m1 = *(const i32x4*)(mb + cc * 32 + jl + 4);                \
            f32x4 d0 = *(const f32x4*)(db + cc * 32 + jl);                    \
            f32x4 d1 = *(const f32x4*)(db + cc * 32 + jl + 4);                \
            bf16x8 pa;                                                        \
            _Pragma("unroll")                                                 \
            for (int e = 0; e < 4; ++e) {                                     \
                float t0 = srow + d0[e];                                      \
                float f0 = fmaxf(t0, 0.01f * t0);                             \
                float w0 = __expf(f0);                                        \
                w0 = (m0[e] > 0) ? w0 : 0.f;                                  \
                zacc += w0;                                                   \
                pa[e] = (__bf16)w0;                                           \
                float t1 = srow + d1[e];                                      \
                float f1 = fmaxf(t1, 0.01f * t1);                             \
                float w1 = __expf(f1);                                        \
                w1 = (m1[e] > 0) ? w1 : 0.f;                                  \
                zacc += w1;                                                   \
                pa[4 + e] = (__bf16)w1;                                       \
            }                                                                 \
            acc0 = __builtin_amdgcn_mfma_f32_16x16x32_bf16(                   \
                pa, __builtin_bit_cast(bf16x8, bset[P][cc * 4 + 0]), acc0, 0, 0, 0); \
            acc1 = __builtin_amdgcn_mfma_f32_16x16x32_bf16(                   \
                pa, __builtin_bit_cast(bf16x8, bset[P][cc * 4 + 1]), acc1, 0, 0, 0); \
            acc2 = __builtin_amdgcn_mfma_f32_16x16x32_bf16(                   \
                pa, __builtin_bit_cast(bf16x8, bset[P][cc * 4 + 2]), acc2, 0, 0, 0); \
            acc3 = __builtin_amdgcn_mfma_f32_16x16x32_bf16(                   \
                pa, __builtin_bit_cast(bf16x8, bset[P][cc * 4 + 3]), acc3, 0, 0, 0); \
        }                                                                     \
    } while (0)

#define BODY_FULL(P)                                                          \
    do {                                                                      \
        STAGE((P) ^ 1, tt + 1);                                               \
        BLOAD((P) ^ 1, tt + 1);                                               \
        asm volatile("s_waitcnt vmcnt(13)" ::: "memory");                     \
        __builtin_amdgcn_sched_barrier(0);                                    \
        __builtin_amdgcn_s_barrier();                                         \
        __builtin_amdgcn_sched_barrier(0);                                    \
        COMPUTE(tt, P, P);                                                    \
        __builtin_amdgcn_s_barrier();                                         \
        ++tt;                                                                 \
    } while (0)

    int tt = 0;
    STAGE(0, 0);      // prologue: tile 0 in flight
    BLOAD(0, 0);

    for (int it = 0; it < 23; ++it) {   // tiles 0..45
        BODY_FULL(0);
        BODY_FULL(1);
    }
    BODY_FULL(0);                       // tile 46 (stages 47)
    // tile 47: nothing left to stage
    asm volatile("s_waitcnt vmcnt(0)" ::: "memory");
    __builtin_amdgcn_sched_barrier(0);
    __builtin_amdgcn_s_barrier();
    __builtin_amdgcn_sched_barrier(0);
    COMPUTE(47, 1, 1);

#undef BODY_FULL
#undef COMPUTE
#undef BLOAD
#undef STAGE

    // block reduce: 4 wave partials -> (16 x 64) tile, normalize, + bias
    __syncthreads();
    float* red  = (float*)lm;          // [4][1024]
    float* redz = red + 4096;          // [4][16]
    #pragma unroll
    for (int r = 0; r < 4; ++r) {
        int orow = kg * 4 + r;         // C/D: row = 4*(lane>>4)+reg, col = lane&15
        red[wid * 1024 + orow * 64 + row]      = acc0[r];
        red[wid * 1024 + orow * 64 + row + 16] = acc1[r];
        red[wid * 1024 + orow * 64 + row + 32] = acc2[r];
        red[wid * 1024 + orow * 64 + row + 48] = acc3[r];
    }
    zacc += __shfl_xor(zacc, 16);
    zacc += __shfl_xor(zacc, 32);
    if (lane < 16) redz[wid * 16 + lane] = zacc;
    __syncthreads();
    #pragma unroll
    for (int k = 0; k < 4; ++k) {
        int idx = k * 256 + t;
        int i   = idx >> 6;
        float sv = red[idx] + red[1024 + idx] + red[2048 + idx] + red[3072 + idx];
        float z  = redz[i] + redz[16 + i] + redz[32 + i] + redz[48 + i];
        z = (z != 0.f) ? z : 1.f;
        out[(size_t)g * 1024 + idx] = sv / z + bias[idx & 63];
    }
}

extern "C" void kernel_launch(void* const* d_in, const int* in_sizes, int n_in,
                              void* d_out, int out_size, void* d_ws, size_t ws_size,
                              hipStream_t stream) {
    const float* x    = (const float*)d_in[0];
    const int*   mask = (const int*)d_in[1];
    const float* W    = (const float*)d_in[2];
    const float* wa   = (const float*)d_in[3];
    const float* bias = (const float*)d_in[4];
    float* out = (float*)d_out;

    char* ws = (char*)d_ws;
    const size_t whB_bytes = (size_t)Nn * 64 * 2;   // 1.5 MB
    const size_t vec_bytes = (size_t)Nn * 4;        // 48 KB
    __bf16* whB = (__bf16*)ws;
    float*  src = (float*)(ws + whB_bytes);
    float*  dst = (float*)(ws + whB_bytes + vec_bytes);

    prep_kernel<<<Nn / 64, 256, 0, stream>>>(x, W, wa, whB, src, dst);
    attn_kernel<<<Nn / 16, 256, 0, stream>>>(mask, whB, src, dst, bias, out);
}

// Round 5
// 141.833 us; speedup vs baseline: 2.0123x; 1.0072x over previous
//
#include <hip/hip_runtime.h>
#include <hip/hip_bf16.h>
#include <cstddef>
#include <cstdint>

#define Nn 12288
#define MSTRIDE 264        // ints per mask row in LDS (16B-aligned, 4-bank row skew)
#define DSTOFF (2 * 16 * MSTRIDE)   // int offset of dst slots in lm
#define LOG2E 1.44269504088896340736f

typedef __bf16 bf16x8 __attribute__((ext_vector_type(8)));
typedef float  f32x4  __attribute__((ext_vector_type(4)));
typedef int    i32x4  __attribute__((ext_vector_type(4)));

__device__ __forceinline__ void gload_lds16_nt(const void* g, void* l) {
    __builtin_amdgcn_global_load_lds(
        (const __attribute__((address_space(1))) void*)g,
        (__attribute__((address_space(3))) void*)l, 16, 0, 2 /*nt*/);
}
__device__ __forceinline__ void gload_lds4(const void* g, void* l) {
    __builtin_amdgcn_global_load_lds(
        (const __attribute__((address_space(1))) void*)g,
        (__attribute__((address_space(3))) void*)l, 4, 0, 0);
}

// ---------------------------------------------------------------------------
// Kernel 1: wh = x @ W; whB in MFMA-fragment order; src/dst PRESCALED by
// log2(e) so the attn kernel can use native exp2.
// ---------------------------------------------------------------------------
__global__ __launch_bounds__(256) void prep_kernel(
    const float* __restrict__ x, const float* __restrict__ W,
    const float* __restrict__ wa, __bf16* __restrict__ whB,
    float* __restrict__ src, float* __restrict__ dst)
{
    __shared__ float  Wl[64 * 64];
    __shared__ float  Xl[64 * 64];
    __shared__ __bf16 whl[64 * 72];
    int t = threadIdx.x;
    int R0 = blockIdx.x * 64;
    for (int i = t; i < 4096; i += 256) {
        Wl[i] = W[i];
        Xl[i] = x[(size_t)R0 * 64 + i];
    }
    __syncthreads();
    int c   = t & 63;
    int r16 = (t >> 6) * 16;
    float vals[16];
    #pragma unroll
    for (int k = 0; k < 16; ++k) vals[k] = 0.f;
    #pragma unroll 16
    for (int kk = 0; kk < 64; ++kk) {
        float wv = Wl[kk * 64 + c];
        #pragma unroll
        for (int k = 0; k < 16; ++k)
            vals[k] = fmaf(Xl[(r16 + k) * 64 + kk], wv, vals[k]);
    }
    #pragma unroll
    for (int k = 0; k < 16; ++k) whl[c * 72 + r16 + k] = (__bf16)vals[k];
    __syncthreads();
    if (t < 64) {
        float s = 0.f, d = 0.f;
        #pragma unroll 16
        for (int cc = 0; cc < 64; ++cc) {
            float v = (float)whl[cc * 72 + t];
            s = fmaf(v, wa[cc], s);
            d = fmaf(v, wa[64 + cc], d);
        }
        src[R0 + t] = s * LOG2E;      // prescale: exp(x) = exp2(x*log2e)
        dst[R0 + t] = d * LOG2E;
    }
    #pragma unroll
    for (int gg = 0; gg < 2; ++gg) {
        int gidx   = t * 2 + gg;
        int jc_loc = gidx >> 8;
        int q      = (gidx >> 6) & 3;
        int lane   = gidx & 63;
        int crow   = (lane & 15) + 16 * q;
        int jrow   = jc_loc * 32 + (lane >> 4) * 8;
        bf16x8 v = *(const bf16x8*)&whl[crow * 72 + jrow];
        int jc = blockIdx.x * 2 + jc_loc;
        *(bf16x8*)&whB[((size_t)(jc * 4 + q) * 64 + lane) * 8] = v;
    }
}

// ---------------------------------------------------------------------------
// Kernel 2: identical pipeline to R4 (vmcnt(13), dbuf LDS, nt mask staging);
// VALU cut: exp2 on prescaled inputs, Z via ones-MFMA instead of scalar adds.
// ---------------------------------------------------------------------------
__global__ __launch_bounds__(256) void attn_kernel(
    const int* __restrict__ mask, const __bf16* __restrict__ whB,
    const float* __restrict__ src, const float* __restrict__ dstv,
    const float* __restrict__ bias, float* __restrict__ out)
{
    __shared__ int lm[DSTOFF + 2 * 256];   // mask dbuf [2][16][264] + dst dbuf [2][4][64]

    int t    = threadIdx.x;
    int lane = t & 63;
    int wid  = t >> 6;
    int g    = blockIdx.x;
    int row  = lane & 15;
    int kg   = lane >> 4;
    int jl   = kg * 8;

    float srow = src[g * 16 + row];
    asm volatile("" :: "v"(srow));   // resolve before pipeline starts

    bf16x8 vones;
    #pragma unroll
    for (int e = 0; e < 8; ++e) vones[e] = (__bf16)1.0f;

    i32x4 bset[2][8];
    f32x4 acc0 = {0.f, 0.f, 0.f, 0.f}, acc1 = acc0, acc2 = acc0, acc3 = acc0;
    f32x4 accZ = acc0;

#define STAGE(B, TT)                                                          \
    do {                                                                      \
        _Pragma("unroll")                                                     \
        for (int rr = 0; rr < 4; ++rr) {                                      \
            int rs = wid * 4 + rr;                                            \
            gload_lds16_nt(mask + (size_t)(g * 16 + rs) * Nn + (TT) * 256 +   \
                               lane * 4,                                      \
                           &lm[(B) * 4224 + rs * MSTRIDE]);                   \
        }                                                                     \
        gload_lds4(dstv + (TT) * 256 + wid * 64 + lane,                       \
                   &lm[DSTOFF + (B) * 256 + wid * 64]);                       \
    } while (0)

#define BLOAD(P, TT)                                                          \
    do {                                                                      \
        const char* _b0 = (const char*)whB +                                  \
                          ((size_t)((TT) * 8 + wid * 2)) * 4096 +             \
                          (size_t)lane * 16;                                  \
        const char* _b1 = _b0 + 4096;                                         \
        asm volatile("global_load_dwordx4 %0, %1, off"                        \
                     : "=v"(bset[P][0]) : "v"(_b0));                          \
        asm volatile("global_load_dwordx4 %0, %1, off offset:1024"            \
                     : "=v"(bset[P][1]) : "v"(_b0));                          \
        asm volatile("global_load_dwordx4 %0, %1, off offset:2048"            \
                     : "=v"(bset[P][2]) : "v"(_b0));                          \
        asm volatile("global_load_dwordx4 %0, %1, off offset:3072"            \
                     : "=v"(bset[P][3]) : "v"(_b0));                          \
        asm volatile("global_load_dwordx4 %0, %1, off"                        \
                     : "=v"(bset[P][4]) : "v"(_b1));                          \
        asm volatile("global_load_dwordx4 %0, %1, off offset:1024"            \
                     : "=v"(bset[P][5]) : "v"(_b1));                          \
        asm volatile("global_load_dwordx4 %0, %1, off offset:2048"            \
                     : "=v"(bset[P][6]) : "v"(_b1));                          \
        asm volatile("global_load_dwordx4 %0, %1, off offset:3072"            \
                     : "=v"(bset[P][7]) : "v"(_b1));                          \
    } while (0)

#define COMPUTE(TT, B, P)                                                     \
    do {                                                                      \
        const int*   mb = &lm[(B) * 4224 + row * MSTRIDE + wid * 64];         \
        const float* db = (const float*)&lm[DSTOFF + (B) * 256 + wid * 64];   \
        _Pragma("unroll")                                                     \
        for (int cc = 0; cc < 2; ++cc) {                                      \
            i32x4 m0 = *(const i32x4*)(mb + cc * 32 + jl);                    \
            i32x4 m1 = *(const i32x4*)(mb + cc * 32 + jl + 4);                \
            f32x4 d0 = *(const f32x4*)(db + cc * 32 + jl);                    \
            f32x4 d1 = *(const f32x4*)(db + cc * 32 + jl + 4);                \
            bf16x8 pa;                                                        \
            _Pragma("unroll")                                                 \
            for (int e = 0; e < 4; ++e) {                                     \
                float t0 = srow + d0[e];                                      \
                float f0 = fmaxf(t0, 0.01f * t0);                             \
                float w0 = __builtin_amdgcn_exp2f(f0);                        \
                w0 = (m0[e] > 0) ? w0 : 0.f;                                  \
                pa[e] = (__bf16)w0;                                           \
                float t1 = srow + d1[e];                                      \
                float f1 = fmaxf(t1, 0.01f * t1);                             \
                float w1 = __builtin_amdgcn_exp2f(f1);                        \
                w1 = (m1[e] > 0) ? w1 : 0.f;                                  \
                pa[4 + e] = (__bf16)w1;                                       \
            }                                                                 \
            acc0 = __builtin_amdgcn_mfma_f32_16x16x32_bf16(                   \
                pa, __builtin_bit_cast(bf16x8, bset[P][cc * 4 + 0]), acc0, 0, 0, 0); \
            acc1 = __builtin_amdgcn_mfma_f32_16x16x32_bf16(                   \
                pa, __builtin_bit_cast(bf16x8, bset[P][cc * 4 + 1]), acc1, 0, 0, 0); \
            acc2 = __builtin_amdgcn_mfma_f32_16x16x32_bf16(                   \
                pa, __builtin_bit_cast(bf16x8, bset[P][cc * 4 + 2]), acc2, 0, 0, 0); \
            acc3 = __builtin_amdgcn_mfma_f32_16x16x32_bf16(                   \
                pa, __builtin_bit_cast(bf16x8, bset[P][cc * 4 + 3]), acc3, 0, 0, 0); \
            accZ = __builtin_amdgcn_mfma_f32_16x16x32_bf16(                   \
                pa, vones, accZ, 0, 0, 0);                                    \
        }                                                                     \
    } while (0)

#define BODY_FULL(P)                                                          \
    do {                                                                      \
        STAGE((P) ^ 1, tt + 1);                                               \
        BLOAD((P) ^ 1, tt + 1);                                               \
        asm volatile("s_waitcnt vmcnt(13)" ::: "memory");                     \
        __builtin_amdgcn_sched_barrier(0);                                    \
        __builtin_amdgcn_s_barrier();                                         \
        __builtin_amdgcn_sched_barrier(0);                                    \
        COMPUTE(tt, P, P);                                                    \
        __builtin_amdgcn_s_barrier();                                         \
        ++tt;                                                                 \
    } while (0)

    int tt = 0;
    STAGE(0, 0);      // prologue: tile 0 in flight
    BLOAD(0, 0);

    for (int it = 0; it < 23; ++it) {   // tiles 0..45
        BODY_FULL(0);
        BODY_FULL(1);
    }
    BODY_FULL(0);                       // tile 46 (stages 47)
    asm volatile("s_waitcnt vmcnt(0)" ::: "memory");
    __builtin_amdgcn_sched_barrier(0);
    __builtin_amdgcn_s_barrier();
    __builtin_amdgcn_sched_barrier(0);
    COMPUTE(47, 1, 1);

#undef BODY_FULL
#undef COMPUTE
#undef BLOAD
#undef STAGE

    // block reduce: 4 wave partials -> (16 x 64) tile, normalize, + bias
    __syncthreads();
    float* red  = (float*)lm;          // [4][1024]
    float* redz = red + 4096;          // [4][16]
    #pragma unroll
    for (int r = 0; r < 4; ++r) {
        int orow = kg * 4 + r;         // C/D: row = 4*(lane>>4)+reg, col = lane&15
        red[wid * 1024 + orow * 64 + row]      = acc0[r];
        red[wid * 1024 + orow * 64 + row + 16] = acc1[r];
        red[wid * 1024 + orow * 64 + row + 32] = acc2[r];
        red[wid * 1024 + orow * 64 + row + 48] = acc3[r];
    }
    // accZ: Z for output-row kg*4+r, replicated across cols; col-0 lanes write
    if (row == 0) {
        #pragma unroll
        for (int r = 0; r < 4; ++r) redz[wid * 16 + kg * 4 + r] = accZ[r];
    }
    __syncthreads();
    #pragma unroll
    for (int k = 0; k < 4; ++k) {
        int idx = k * 256 + t;
        int i   = idx >> 6;
        float sv = red[idx] + red[1024 + idx] + red[2048 + idx] + red[3072 + idx];
        float z  = redz[i] + redz[16 + i] + redz[32 + i] + redz[48 + i];
        z = (z != 0.f) ? z : 1.f;
        out[(size_t)g * 1024 + idx] = sv / z + bias[idx & 63];
    }
}

extern "C" void kernel_launch(void* const* d_in, const int* in_sizes, int n_in,
                              void* d_out, int out_size, void* d_ws, size_t ws_size,
                              hipStream_t stream) {
    const float* x    = (const float*)d_in[0];
    const int*   mask = (const int*)d_in[1];
    const float* W    = (const float*)d_in[2];
    const float* wa   = (const float*)d_in[3];
    const float* bias = (const float*)d_in[4];
    float* out = (float*)d_out;

    char* ws = (char*)d_ws;
    const size_t whB_bytes = (size_t)Nn * 64 * 2;   // 1.5 MB
    const size_t vec_bytes = (size_t)Nn * 4;        // 48 KB
    __bf16* whB = (__bf16*)ws;
    float*  src = (float*)(ws + whB_bytes);
    float*  dst = (float*)(ws + whB_bytes + vec_bytes);

    prep_kernel<<<Nn / 64, 256, 0, stream>>>(x, W, wa, whB, src, dst);
    attn_kernel<<<Nn / 16, 256, 0, stream>>>(mask, whB, src, dst, bias, out);
}